// Round 8
// baseline (224.293 us; speedup 1.0000x reference)
//
#include <hip/hip_runtime.h>
#include <hip/hip_bf16.h>

#define CC 64
#define HW 9216
#define IMG 96
#define SPLITS 8
#define SPLEN 1152            // 9216 / 8
#define ITERS 18              // 1152 / 64
#define LOG2E 1.44269504f

typedef _Float16 f16;
typedef __attribute__((ext_vector_type(8))) _Float16 f16x8;
typedef __attribute__((ext_vector_type(4))) _Float16 f16x4;
typedef __attribute__((ext_vector_type(4))) float f32x4;

// ---------------- dilated 3x3 conv (pad=2, dil=2)
// writes yq = f16(log2e * y) in Q layout (flat chw) and kt[m*64+c] = f16(y) (K^T)
// weights read via block-uniform global loads -> s_load (SMEM pipe, no LDS)
__global__ __launch_bounds__(256) void conv_dil_kernel(
    const float* __restrict__ x, const float* __restrict__ dW, const float* __restrict__ db,
    f16* __restrict__ yq, f16* __restrict__ kt)
{
    const int b = blockIdx.x;            // 16 co-groups * 36 chunks
    const int cog = b / 36, chunk = b % 36;
    const int t = threadIdx.x;
    const int m = chunk * 256 + t;
    const int h = m / IMG, w = m % IMG;

    int off[9]; float fv[9];
    #pragma unroll
    for (int kh = 0; kh < 3; ++kh)
        #pragma unroll
        for (int kw = 0; kw < 3; ++kw) {
            int hh = h + 2 * kh - 2, ww = w + 2 * kw - 2;
            bool ok = (hh >= 0 && hh < IMG && ww >= 0 && ww < IMG);
            int hc = min(max(hh, 0), IMG - 1), wc = min(max(ww, 0), IMG - 1);
            off[kh * 3 + kw] = hc * IMG + wc;
            fv[kh * 3 + kw] = ok ? 1.f : 0.f;
        }
    const int co0 = cog * 4;
    float acc[4];
    #pragma unroll
    for (int cc = 0; cc < 4; ++cc) acc[cc] = db[co0 + cc];

    #pragma unroll 2
    for (int ci = 0; ci < CC; ++ci) {
        const float* xp = x + ci * HW;
        float tv[9];
        #pragma unroll
        for (int k = 0; k < 9; ++k) tv[k] = xp[off[k]] * fv[k];
        #pragma unroll
        for (int cc = 0; cc < 4; ++cc) {
            const float* wp = dW + (co0 + cc) * 576 + ci * 9;   // block-uniform -> s_load
            #pragma unroll
            for (int k = 0; k < 9; ++k) acc[cc] += wp[k] * tv[k];
        }
    }
    #pragma unroll
    for (int cc = 0; cc < 4; ++cc) {
        yq[(co0 + cc) * HW + m] = (f16)(acc[cc] * LOG2E);   // log2e-scaled Q copy
        kt[m * 64 + (co0 + cc)] = (f16)acc[cc];             // unscaled K^T[m][c]
    }
}

// ---------------- 1x1 conv: writes vt[c][m] (transposed V-matrix, f16); LDS weights [ci][cc]
__global__ __launch_bounds__(256) void conv1x1_kernel(
    const float* __restrict__ x, const float* __restrict__ cW, const float* __restrict__ cb,
    f16* __restrict__ vt)
{
    __shared__ float wsh[64 * 4];        // [ci][cc]
    const int b = blockIdx.x;            // 16 co-groups * 36 chunks
    const int cog = b / 36, chunk = b % 36;
    const int t = threadIdx.x;
    const int co0 = cog * 4;
    if (t < 256) wsh[t] = cW[(co0 + (t & 3)) * CC + (t >> 2)];
    __syncthreads();

    const int m = chunk * 256 + t;
    float acc[4];
    #pragma unroll
    for (int cc = 0; cc < 4; ++cc) acc[cc] = cb[co0 + cc];
    #pragma unroll 4
    for (int ci = 0; ci < CC; ++ci) {
        float xv = x[ci * HW + m];
        float4 wv = *(const float4*)&wsh[ci * 4];            // uniform b128 broadcast
        acc[0] += wv.x * xv; acc[1] += wv.y * xv;
        acc[2] += wv.z * xv; acc[3] += wv.w * xv;
    }
    #pragma unroll
    for (int cc = 0; cc < 4; ++cc)
        vt[(m & 63) * HW + (co0 + cc) * 144 + (m >> 6)] = (f16)acc[cc];
}

// ---------------- MFMA flash attention, transposed-S^T scheme
// Each lane owns one query row's 64 scores per iter (16 regs + 3 replicas over g).
__global__ __launch_bounds__(256, 4) void attn_kernel(
    const f16* __restrict__ kt, const f16* __restrict__ vt, const f16* __restrict__ yq,
    f16* __restrict__ acc_ws, float* __restrict__ m_ws, float* __restrict__ l_ws)
{
    __shared__ f16 sKT[64 * 72];        // [key_local][c], row stride 144 B
    __shared__ f16 sVT[64 * 72];        // [channel][key_local]
    __shared__ f16 sPS[4 * 16 * 72];    // per-wave P [query_local][key_local]

    const int t = threadIdx.x;
    const int L = t & 63, w = t >> 6;
    const int g = L >> 4, c16 = L & 15;
    const int qb = blockIdx.x >> 3, sp = blockIdx.x & 7;
    const int n0 = qb * 64;
    const int mbase = sp * SPLEN;
    f16* psw = (f16*)sPS + w * 16 * 72;

    // Q fragments (log2e-scaled). Same register layout serves as B-operand for S^T.
    f16x8 qa[2];
    #pragma unroll
    for (int kc = 0; kc < 2; ++kc)
        qa[kc] = *(const f16x8*)(yq + (n0 + w * 16 + c16) * 64 + g * 8 + kc * 32);

    float mi = -1e30f, li = 0.f;
    f32x4 acc[4];
    #pragma unroll
    for (int ct = 0; ct < 4; ++ct) acc[ct] = (f32x4){0.f, 0.f, 0.f, 0.f};

    const float TH = 0.3f * LOG2E;      // mask threshold in log2e-scaled units

    for (int it = 0; it < ITERS; ++it) {
        const int m0 = mbase + it * 64;
        __syncthreads();
        #pragma unroll
        for (int rep = 0; rep < 2; ++rep) {
            int idx = t + rep * 256;
            int row = idx >> 3, ch = idx & 7;
            *(uint4*)&sKT[row * 72 + ch * 8] = *(const uint4*)&kt[(m0 + row) * 64 + ch * 8];
            *(uint4*)&sVT[row * 72 + ch * 8] = *(const uint4*)&vt[row * HW + m0 + ch * 8];
        }
        __syncthreads();

        // S^T = K Q^T : lane (g,c16) gets s[mt][j] = log2e*S[query w*16+c16][key m0+mt*16+4g+j]
        f32x4 s[4];
        #pragma unroll
        for (int mt = 0; mt < 4; ++mt) {
            f32x4 a0 = (f32x4){0.f, 0.f, 0.f, 0.f};
            #pragma unroll
            for (int kc = 0; kc < 2; ++kc) {
                f16x8 kb = *(const f16x8*)&sKT[(mt * 16 + c16) * 72 + g * 8 + kc * 32];
                a0 = __builtin_amdgcn_mfma_f32_16x16x32_f16(kb, qa[kc], a0, 0, 0, 0);
            }
            s[mt] = a0;
        }
        // threshold mask to ZERO (|S|>0.3  <=>  |s2|>0.3*log2e)
        #pragma unroll
        for (int mt = 0; mt < 4; ++mt)
            #pragma unroll
            for (int j = 0; j < 4; ++j)
                s[mt][j] = (fabsf(s[mt][j]) > TH) ? s[mt][j] : 0.f;

        // row max: 15 local fmax + 2 shfls (lane owns its whole row)
        float mx = s[0][0];
        #pragma unroll
        for (int mt = 0; mt < 4; ++mt)
            #pragma unroll
            for (int j = 0; j < 4; ++j) mx = fmaxf(mx, s[mt][j]);
        mx = fmaxf(mx, __shfl_xor(mx, 16, 64));
        mx = fmaxf(mx, __shfl_xor(mx, 32, 64));
        float mnew = fmaxf(mi, mx);
        float alpha = exp2f(mi - mnew);
        mi = mnew;

        // p = exp2(s - mnew); local sum + 2 shfls
        float p[16], ls = 0.f;
        #pragma unroll
        for (int mt = 0; mt < 4; ++mt)
            #pragma unroll
            for (int j = 0; j < 4; ++j) {
                float pv = exp2f(s[mt][j] - mnew);
                p[mt * 4 + j] = pv;
                ls += pv;
            }
        ls += __shfl_xor(ls, 16, 64);
        ls += __shfl_xor(ls, 32, 64);
        li = li * alpha + ls;

        // write P: 4 aligned b64 stores (4-lane/bank-pair floor, conflict-free)
        #pragma unroll
        for (int mt = 0; mt < 4; ++mt) {
            f16x4 v4 = {(f16)p[mt * 4 + 0], (f16)p[mt * 4 + 1],
                        (f16)p[mt * 4 + 2], (f16)p[mt * 4 + 3]};
            *(f16x4*)&psw[c16 * 72 + mt * 16 + 4 * g] = v4;
        }

        // rescale acc: rows are queries 4g+j -> fetch their alphas (state in lanes 0..15)
        float aj[4];
        #pragma unroll
        for (int j = 0; j < 4; ++j) aj[j] = __shfl(alpha, 4 * g + j, 64);
        #pragma unroll
        for (int ct = 0; ct < 4; ++ct)
            #pragma unroll
            for (int j = 0; j < 4; ++j) acc[ct][j] *= aj[j];

        // PV: A = P (A-layout from psw; same-wave LDS RAW is ordered), B = V^T tile
        f16x8 pa[2];
        #pragma unroll
        for (int kc = 0; kc < 2; ++kc)
            pa[kc] = *(const f16x8*)&psw[c16 * 72 + g * 8 + kc * 32];
        #pragma unroll
        for (int ct = 0; ct < 4; ++ct)
            #pragma unroll
            for (int kc = 0; kc < 2; ++kc) {
                f16x8 vb = *(const f16x8*)&sVT[(ct * 16 + c16) * 72 + g * 8 + kc * 32];
                acc[ct] = __builtin_amdgcn_mfma_f32_16x16x32_f16(pa[kc], vb, acc[ct], 0, 0, 0);
            }
    }

    // write partials (no divide; merge kernel combines splits)
    const int base = blockIdx.x;
    #pragma unroll
    for (int ct = 0; ct < 4; ++ct)
        #pragma unroll
        for (int j = 0; j < 4; ++j)
            acc_ws[base * 4096 + (w * 16 + 4 * g + j) * 64 + ct * 16 + c16] = (f16)acc[ct][j];
    if (g == 0) {
        m_ws[base * 64 + w * 16 + c16] = mi;    // log2 units
        l_ws[base * 64 + w * 16 + c16] = li;
    }
}

// ---------------- merge splits + residual + transpose to (C, HW); m is in log2 units
__global__ __launch_bounds__(256) void merge_kernel(
    const f16* __restrict__ acc_ws, const float* __restrict__ m_ws, const float* __restrict__ l_ws,
    const float* __restrict__ x, float* __restrict__ out)
{
    __shared__ float wsh[SPLITS * 64];
    __shared__ float att[64 * 65];
    const int qb = blockIdx.x;
    const int t = threadIdx.x;
    if (t < 64) {
        float ms = -1e30f;
        float mv[SPLITS];
        #pragma unroll
        for (int sp = 0; sp < SPLITS; ++sp) {
            mv[sp] = m_ws[(qb * SPLITS + sp) * 64 + t];
            ms = fmaxf(ms, mv[sp]);
        }
        float Lsum = 0.f, ev[SPLITS];
        #pragma unroll
        for (int sp = 0; sp < SPLITS; ++sp) {
            ev[sp] = exp2f(mv[sp] - ms);
            Lsum += l_ws[(qb * SPLITS + sp) * 64 + t] * ev[sp];
        }
        float inv = 1.f / Lsum;
        #pragma unroll
        for (int sp = 0; sp < SPLITS; ++sp)
            wsh[sp * 64 + t] = ev[sp] * inv;
    }
    __syncthreads();
    for (int i = t; i < 4096; i += 256) {
        int r = i >> 6, c = i & 63;
        float v = 0.f;
        #pragma unroll
        for (int sp = 0; sp < SPLITS; ++sp)
            v += (float)acc_ws[(qb * SPLITS + sp) * 4096 + r * 64 + c] * wsh[sp * 64 + r];
        att[c * 65 + r] = v;
    }
    __syncthreads();
    const int n0 = qb * 64;
    for (int i = t; i < 4096; i += 256) {
        int c = i >> 6, r = i & 63;
        int idx = c * HW + n0 + r;
        out[idx] = x[idx] + att[c * 65 + r];
    }
}

extern "C" void kernel_launch(void* const* d_in, const int* in_sizes, int n_in,
                              void* d_out, int out_size, void* d_ws, size_t ws_size,
                              hipStream_t stream)
{
    const float* x  = (const float*)d_in[0];
    const float* dW = (const float*)d_in[1];
    const float* db = (const float*)d_in[2];
    const float* cW = (const float*)d_in[3];
    const float* cb = (const float*)d_in[4];
    float* out = (float*)d_out;

    char* ws = (char*)d_ws;
    f16* yq     = (f16*)(ws);                        // 1,179,648 B
    f16* kt     = (f16*)(ws + 1179648);              // 1,179,648 B
    f16* vt     = (f16*)(ws + 2359296);              // 1,179,648 B
    f16* acc_ws = (f16*)(ws + 3538944);              // 9,437,184 B
    float* m_ws = (float*)(ws + 12976128);           //   294,912 B
    float* l_ws = (float*)(ws + 13271040);           //   294,912 B
                                                     // total 13,565,952 B

    conv_dil_kernel<<<dim3(16 * 36), dim3(256), 0, stream>>>(x, dW, db, yq, kt);
    conv1x1_kernel<<<dim3(16 * 36), dim3(256), 0, stream>>>(x, cW, cb, vt);
    attn_kernel<<<dim3(144 * SPLITS), dim3(256), 0, stream>>>(kt, vt, yq, acc_ws, m_ws, l_ws);
    merge_kernel<<<dim3(144), dim3(256), 0, stream>>>(acc_ws, m_ws, l_ws, x, out);
}

// Round 10
// 180.617 us; speedup vs baseline: 1.2418x; 1.2418x over previous
//
#include <hip/hip_runtime.h>
#include <hip/hip_bf16.h>

#define CC 64
#define HW 9216
#define IMG 96
#define PW 100                // padded width/height
#define SPLITS 8
#define SPLEN 1152            // 9216 / 8
#define ITERS 18              // 1152 / 64
#define LOG2E 1.44269504f

typedef _Float16 f16;
typedef __attribute__((ext_vector_type(8))) _Float16 f16x8;
typedef __attribute__((ext_vector_type(4))) _Float16 f16x4;
typedef __attribute__((ext_vector_type(2))) _Float16 f16x2;
typedef __attribute__((ext_vector_type(4))) float f32x4;

// ---------------- pad x into f16 [64][100*100] image (zero borders of 2)
__global__ __launch_bounds__(256) void prepad_kernel(
    const float* __restrict__ x, f16* __restrict__ xpad)
{
    int i = blockIdx.x * 256 + threadIdx.x;      // 64 * 10000
    if (i >= CC * PW * PW) return;
    int ci = i / (PW * PW), p = i % (PW * PW);
    int r = p / PW, c = p % PW;
    bool inside = (r >= 2 && r < IMG + 2 && c >= 2 && c < IMG + 2);
    float v = inside ? x[ci * HW + (r - 2) * IMG + (c - 2)] : 0.f;
    xpad[i] = (f16)v;
}

// ---------------- dilated 3x3 conv (pad=2, dil=2) from padded f16 image
// co=1 per block, 2 outputs per thread; writes BOTH layouts:
//   yq[co*HW+m] (flat chw -> Q rows via raw reshape)  and  kt[m*64+co] (K^T)
__global__ __launch_bounds__(256) void conv_dil_kernel(
    const f16* __restrict__ xpad, const float* __restrict__ dW, const float* __restrict__ db,
    f16* __restrict__ yq, f16* __restrict__ kt)
{
    __shared__ float wsh[576];
    const int co = blockIdx.x / 18, chunk = blockIdx.x % 18;   // grid 64*18
    const int t = threadIdx.x;
    for (int i = t; i < 576; i += 256) wsh[i] = dW[co * 576 + i];
    __syncthreads();

    const int m0 = chunk * 512 + 2 * t;
    const int h = m0 / IMG, w = m0 % IMG;        // w even
    // image taps (h+2kh-2, w+2kw-2) -> padded coords (h+2kh, w+2kw); base (h, w)
    const int pbase = h * PW + w;

    float a0 = db[co], a1 = a0;
    #pragma unroll 2
    for (int ci = 0; ci < CC; ++ci) {
        const f16* bp = xpad + ci * (PW * PW) + pbase;
        #pragma unroll
        for (int kh = 0; kh < 3; ++kh) {
            const f16* rp = bp + kh * (2 * PW);
            f16x2 A = *(const f16x2*)(rp);       // padded cols w,   w+1
            f16x2 B = *(const f16x2*)(rp + 2);   //             w+2, w+3
            f16x2 C = *(const f16x2*)(rp + 4);   //             w+4, w+5
            const float* wk = &wsh[ci * 9 + kh * 3];
            a0 += wk[0] * (float)A.x; a1 += wk[0] * (float)A.y;
            a0 += wk[1] * (float)B.x; a1 += wk[1] * (float)B.y;
            a0 += wk[2] * (float)C.x; a1 += wk[2] * (float)C.y;
        }
    }
    f16 h0 = (f16)a0, h1 = (f16)a1;
    *(f16x2*)&yq[co * HW + m0] = (f16x2){h0, h1};   // flat chw (Q layout), m0 even
    kt[m0 * 64 + co]       = h0;                    // K^T[m][c]
    kt[(m0 + 1) * 64 + co] = h1;
}

// ---------------- 1x1 conv: writes vt[c][m] (transposed V-matrix, f16); LDS weights [ci][cc]
__global__ __launch_bounds__(256) void conv1x1_kernel(
    const float* __restrict__ x, const float* __restrict__ cW, const float* __restrict__ cb,
    f16* __restrict__ vt)
{
    __shared__ float wsh[64 * 4];        // [ci][cc]
    const int b = blockIdx.x;            // 16 co-groups * 36 chunks
    const int cog = b / 36, chunk = b % 36;
    const int t = threadIdx.x;
    const int co0 = cog * 4;
    if (t < 256) wsh[t] = cW[(co0 + (t & 3)) * CC + (t >> 2)];
    __syncthreads();

    const int m = chunk * 256 + t;
    float acc[4];
    #pragma unroll
    for (int cc = 0; cc < 4; ++cc) acc[cc] = cb[co0 + cc];
    #pragma unroll 4
    for (int ci = 0; ci < CC; ++ci) {
        float xv = x[ci * HW + m];
        float4 wv = *(const float4*)&wsh[ci * 4];            // uniform b128 broadcast
        acc[0] += wv.x * xv; acc[1] += wv.y * xv;
        acc[2] += wv.z * xv; acc[3] += wv.w * xv;
    }
    #pragma unroll
    for (int cc = 0; cc < 4; ++cc)
        vt[(m & 63) * HW + (co0 + cc) * 144 + (m >> 6)] = (f16)acc[cc];
}

// ---------------- MFMA flash attention, transposed-S^T scheme; Q frags from yq (flat chw)
__global__ __launch_bounds__(256, 4) void attn_kernel(
    const f16* __restrict__ kt, const f16* __restrict__ vt, const f16* __restrict__ yq,
    f16* __restrict__ acc_ws, float* __restrict__ m_ws, float* __restrict__ l_ws)
{
    __shared__ f16 sKT[64 * 72];        // [key_local][c], row stride 144 B
    __shared__ f16 sVT[64 * 72];        // [channel][key_local]
    __shared__ f16 sPS[4 * 16 * 72];    // per-wave P [query_local][key_local]

    const int t = threadIdx.x;
    const int L = t & 63, w = t >> 6;
    const int g = L >> 4, c16 = L & 15;
    const int qb = blockIdx.x >> 3, sp = blockIdx.x & 7;
    const int n0 = qb * 64;
    const int mbase = sp * SPLEN;
    f16* psw = (f16*)sPS + w * 16 * 72;

    // Q fragments: Q[row][c] = yq_flat[row*64+c] (raw-reshape semantics)
    f16x8 qa[2];
    #pragma unroll
    for (int kc = 0; kc < 2; ++kc)
        qa[kc] = *(const f16x8*)(yq + (n0 + w * 16 + c16) * 64 + g * 8 + kc * 32);

    float mi = -1e30f, li = 0.f;
    f32x4 acc[4];
    #pragma unroll
    for (int ct = 0; ct < 4; ++ct) acc[ct] = (f32x4){0.f, 0.f, 0.f, 0.f};

    for (int it = 0; it < ITERS; ++it) {
        const int m0 = mbase + it * 64;
        __syncthreads();
        #pragma unroll
        for (int rep = 0; rep < 2; ++rep) {
            int idx = t + rep * 256;
            int row = idx >> 3, ch = idx & 7;
            *(uint4*)&sKT[row * 72 + ch * 8] = *(const uint4*)&kt[(m0 + row) * 64 + ch * 8];
            *(uint4*)&sVT[row * 72 + ch * 8] = *(const uint4*)&vt[row * HW + m0 + ch * 8];
        }
        __syncthreads();

        // S^T = K Q^T : lane (g,c16) gets s[mt][j] = S[query w*16+c16][key m0+mt*16+4g+j]
        f32x4 s[4];
        #pragma unroll
        for (int mt = 0; mt < 4; ++mt) {
            f32x4 a0 = (f32x4){0.f, 0.f, 0.f, 0.f};
            #pragma unroll
            for (int kc = 0; kc < 2; ++kc) {
                f16x8 kb = *(const f16x8*)&sKT[(mt * 16 + c16) * 72 + g * 8 + kc * 32];
                a0 = __builtin_amdgcn_mfma_f32_16x16x32_f16(kb, qa[kc], a0, 0, 0, 0);
            }
            s[mt] = a0;
        }
        // threshold mask to ZERO (unscaled), then scale to log2 units
        #pragma unroll
        for (int mt = 0; mt < 4; ++mt)
            #pragma unroll
            for (int j = 0; j < 4; ++j)
                s[mt][j] = (fabsf(s[mt][j]) > 0.3f) ? s[mt][j] * LOG2E : 0.f;

        // row max: 15 local fmax + 2 shfls (lane owns its whole row)
        float mx = s[0][0];
        #pragma unroll
        for (int mt = 0; mt < 4; ++mt)
            #pragma unroll
            for (int j = 0; j < 4; ++j) mx = fmaxf(mx, s[mt][j]);
        mx = fmaxf(mx, __shfl_xor(mx, 16, 64));
        mx = fmaxf(mx, __shfl_xor(mx, 32, 64));
        float mnew = fmaxf(mi, mx);
        float alpha = exp2f(mi - mnew);
        mi = mnew;

        // p = exp2(s - mnew); local sum + 2 shfls
        float p[16], ls = 0.f;
        #pragma unroll
        for (int mt = 0; mt < 4; ++mt)
            #pragma unroll
            for (int j = 0; j < 4; ++j) {
                float pv = exp2f(s[mt][j] - mnew);
                p[mt * 4 + j] = pv;
                ls += pv;
            }
        ls += __shfl_xor(ls, 16, 64);
        ls += __shfl_xor(ls, 32, 64);
        li = li * alpha + ls;

        // write P: 4 aligned b64 stores (conflict-free)
        #pragma unroll
        for (int mt = 0; mt < 4; ++mt) {
            f16x4 v4 = {(f16)p[mt * 4 + 0], (f16)p[mt * 4 + 1],
                        (f16)p[mt * 4 + 2], (f16)p[mt * 4 + 3]};
            *(f16x4*)&psw[c16 * 72 + mt * 16 + 4 * g] = v4;
        }

        // rescale acc: rows are queries 4g+j -> fetch their alphas (state in lanes 0..15)
        float aj[4];
        #pragma unroll
        for (int j = 0; j < 4; ++j) aj[j] = __shfl(alpha, 4 * g + j, 64);
        #pragma unroll
        for (int ct = 0; ct < 4; ++ct)
            #pragma unroll
            for (int j = 0; j < 4; ++j) acc[ct][j] *= aj[j];

        // PV: A = P (A-layout from psw; same-wave LDS RAW is ordered), B = V^T tile
        f16x8 pa[2];
        #pragma unroll
        for (int kc = 0; kc < 2; ++kc)
            pa[kc] = *(const f16x8*)&psw[c16 * 72 + g * 8 + kc * 32];
        #pragma unroll
        for (int ct = 0; ct < 4; ++ct)
            #pragma unroll
            for (int kc = 0; kc < 2; ++kc) {
                f16x8 vb = *(const f16x8*)&sVT[(ct * 16 + c16) * 72 + g * 8 + kc * 32];
                acc[ct] = __builtin_amdgcn_mfma_f32_16x16x32_f16(pa[kc], vb, acc[ct], 0, 0, 0);
            }
    }

    // write partials (no divide; merge kernel combines splits)
    const int base = blockIdx.x;
    #pragma unroll
    for (int ct = 0; ct < 4; ++ct)
        #pragma unroll
        for (int j = 0; j < 4; ++j)
            acc_ws[base * 4096 + (w * 16 + 4 * g + j) * 64 + ct * 16 + c16] = (f16)acc[ct][j];
    if (g == 0) {
        m_ws[base * 64 + w * 16 + c16] = mi;    // log2 units
        l_ws[base * 64 + w * 16 + c16] = li;
    }
}

// ---------------- merge splits + residual + transpose to (C, HW); m is in log2 units
__global__ __launch_bounds__(256) void merge_kernel(
    const f16* __restrict__ acc_ws, const float* __restrict__ m_ws, const float* __restrict__ l_ws,
    const float* __restrict__ x, float* __restrict__ out)
{
    __shared__ float wsh[SPLITS * 64];
    __shared__ float att[64 * 65];
    const int qb = blockIdx.x;
    const int t = threadIdx.x;
    if (t < 64) {
        float ms = -1e30f;
        float mv[SPLITS];
        #pragma unroll
        for (int sp = 0; sp < SPLITS; ++sp) {
            mv[sp] = m_ws[(qb * SPLITS + sp) * 64 + t];
            ms = fmaxf(ms, mv[sp]);
        }
        float Lsum = 0.f, ev[SPLITS];
        #pragma unroll
        for (int sp = 0; sp < SPLITS; ++sp) {
            ev[sp] = exp2f(mv[sp] - ms);
            Lsum += l_ws[(qb * SPLITS + sp) * 64 + t] * ev[sp];
        }
        float inv = 1.f / Lsum;
        #pragma unroll
        for (int sp = 0; sp < SPLITS; ++sp)
            wsh[sp * 64 + t] = ev[sp] * inv;
    }
    __syncthreads();
    for (int i = t; i < 4096; i += 256) {
        int r = i >> 6, c = i & 63;
        float v = 0.f;
        #pragma unroll
        for (int sp = 0; sp < SPLITS; ++sp)
            v += (float)acc_ws[(qb * SPLITS + sp) * 4096 + r * 64 + c] * wsh[sp * 64 + r];
        att[c * 65 + r] = v;
    }
    __syncthreads();
    const int n0 = qb * 64;
    for (int i = t; i < 4096; i += 256) {
        int c = i >> 6, r = i & 63;
        int idx = c * HW + n0 + r;
        out[idx] = x[idx] + att[c * 65 + r];
    }
}

extern "C" void kernel_launch(void* const* d_in, const int* in_sizes, int n_in,
                              void* d_out, int out_size, void* d_ws, size_t ws_size,
                              hipStream_t stream)
{
    const float* x  = (const float*)d_in[0];
    const float* dW = (const float*)d_in[1];
    const float* db = (const float*)d_in[2];
    const float* cW = (const float*)d_in[3];
    const float* cb = (const float*)d_in[4];
    float* out = (float*)d_out;

    char* ws = (char*)d_ws;
    f16* kt     = (f16*)(ws);                        // 1,179,648 B
    f16* yq     = (f16*)(ws + 1179648);              // 1,179,648 B
    f16* vt     = (f16*)(ws + 2359296);              // 1,179,648 B
    f16* xpad   = (f16*)(ws + 3538944);              // 1,280,000 B
    f16* acc_ws = (f16*)(ws + 4818944);              // 9,437,184 B
    float* m_ws = (float*)(ws + 14256128);           //   294,912 B
    float* l_ws = (float*)(ws + 14551040);           //   294,912 B
                                                     // total 14,845,952 B

    prepad_kernel<<<dim3((CC * PW * PW + 255) / 256), dim3(256), 0, stream>>>(x, xpad);
    conv1x1_kernel<<<dim3(16 * 36), dim3(256), 0, stream>>>(x, cW, cb, vt);
    conv_dil_kernel<<<dim3(64 * 18), dim3(256), 0, stream>>>(xpad, dW, db, yq, kt);
    attn_kernel<<<dim3(144 * SPLITS), dim3(256), 0, stream>>>(kt, vt, yq, acc_ws, m_ws, l_ws);
    merge_kernel<<<dim3(144), dim3(256), 0, stream>>>(acc_ws, m_ws, l_ws, x, out);
}

// Round 11
// 163.043 us; speedup vs baseline: 1.3757x; 1.1078x over previous
//
#include <hip/hip_runtime.h>
#include <hip/hip_bf16.h>

#define CC 64
#define HW 9216
#define IMG 96
#define PW 100                // padded width/height
#define SPLITS 8
#define SPLEN 1152            // 9216 / 8
#define ITERS 18              // 1152 / 64
#define LOG2E 1.44269504f

typedef _Float16 f16;
typedef __attribute__((ext_vector_type(8))) _Float16 f16x8;
typedef __attribute__((ext_vector_type(4))) _Float16 f16x4;
typedef __attribute__((ext_vector_type(2))) _Float16 f16x2;
typedef __attribute__((ext_vector_type(4))) float f32x4;

// ---------------- pad x into f16 [64][100*100] image (zero borders of 2)
__global__ __launch_bounds__(256) void prepad_kernel(
    const float* __restrict__ x, f16* __restrict__ xpad)
{
    int i = blockIdx.x * 256 + threadIdx.x;      // 64 * 10000
    if (i >= CC * PW * PW) return;
    int ci = i / (PW * PW), p = i % (PW * PW);
    int r = p / PW, c = p % PW;
    bool inside = (r >= 2 && r < IMG + 2 && c >= 2 && c < IMG + 2);
    float v = inside ? x[ci * HW + (r - 2) * IMG + (c - 2)] : 0.f;
    xpad[i] = (f16)v;
}

// ---------------- dilated 3x3 conv (pad=2, dil=2) from padded f16 image
// co=1 per block, 4 outputs/thread (8-col tap window = 2 aligned f16x4 loads/row);
// weights via block-uniform global reads -> s_load. Writes yq (flat chw) and kt (K^T).
__global__ __launch_bounds__(256) void conv_dil_kernel(
    const f16* __restrict__ xpad, const float* __restrict__ dW, const float* __restrict__ db,
    f16* __restrict__ yq, f16* __restrict__ kt)
{
    const int co = blockIdx.x / 9, chunk = blockIdx.x % 9;   // grid 64*9
    const int t = threadIdx.x;
    const int m0 = chunk * 1024 + 4 * t;         // m0 % 4 == 0, 4-out group never wraps a row
    const int h = m0 / IMG, w = m0 % IMG;        // w % 4 == 0
    const int pbase = h * PW + w;
    const float* wco = dW + co * 576;            // block-uniform -> scalar loads

    float a0, a1, a2, a3;
    a0 = a1 = a2 = a3 = db[co];
    #pragma unroll 2
    for (int ci = 0; ci < CC; ++ci) {
        const f16* rp0 = xpad + ci * (PW * PW) + pbase;
        const float* wk = wco + ci * 9;
        #pragma unroll
        for (int kh = 0; kh < 3; ++kh) {
            const f16* rp = rp0 + kh * (2 * PW);
            f16x4 L0 = *(const f16x4*)(rp);      // padded cols w..w+3 (8B aligned)
            f16x4 L1 = *(const f16x4*)(rp + 4);  //             w+4..w+7
            float e0 = (float)L0.x, e1 = (float)L0.y, e2 = (float)L0.z, e3 = (float)L0.w;
            float e4 = (float)L1.x, e5 = (float)L1.y, e6 = (float)L1.z, e7 = (float)L1.w;
            float w0 = wk[kh * 3 + 0], w1 = wk[kh * 3 + 1], w2 = wk[kh * 3 + 2];
            a0 += w0 * e0 + w1 * e2 + w2 * e4;
            a1 += w0 * e1 + w1 * e3 + w2 * e5;
            a2 += w0 * e2 + w1 * e4 + w2 * e6;
            a3 += w0 * e3 + w1 * e5 + w2 * e7;
        }
    }
    f16 h0 = (f16)a0, h1 = (f16)a1, h2 = (f16)a2, h3 = (f16)a3;
    *(f16x4*)&yq[co * HW + m0] = (f16x4){h0, h1, h2, h3};   // flat chw (Q layout)
    kt[(m0 + 0) * 64 + co] = h0;                            // K^T[m][c]
    kt[(m0 + 1) * 64 + co] = h1;
    kt[(m0 + 2) * 64 + co] = h2;
    kt[(m0 + 3) * 64 + co] = h3;
}

// ---------------- 1x1 conv: writes vt[c][m] (transposed V-matrix, f16); LDS weights [ci][cc]
__global__ __launch_bounds__(256) void conv1x1_kernel(
    const float* __restrict__ x, const float* __restrict__ cW, const float* __restrict__ cb,
    f16* __restrict__ vt)
{
    __shared__ float wsh[64 * 4];        // [ci][cc]
    const int b = blockIdx.x;            // 16 co-groups * 36 chunks
    const int cog = b / 36, chunk = b % 36;
    const int t = threadIdx.x;
    const int co0 = cog * 4;
    if (t < 256) wsh[t] = cW[(co0 + (t & 3)) * CC + (t >> 2)];
    __syncthreads();

    const int m = chunk * 256 + t;
    float acc[4];
    #pragma unroll
    for (int cc = 0; cc < 4; ++cc) acc[cc] = cb[co0 + cc];
    #pragma unroll 4
    for (int ci = 0; ci < CC; ++ci) {
        float xv = x[ci * HW + m];
        float4 wv = *(const float4*)&wsh[ci * 4];            // uniform b128 broadcast
        acc[0] += wv.x * xv; acc[1] += wv.y * xv;
        acc[2] += wv.z * xv; acc[3] += wv.w * xv;
    }
    #pragma unroll
    for (int cc = 0; cc < 4; ++cc)
        vt[(m & 63) * HW + (co0 + cc) * 144 + (m >> 6)] = (f16)acc[cc];
}

// ---------------- MFMA flash attention, transposed-S^T scheme, slim softmax
__global__ __launch_bounds__(256, 4) void attn_kernel(
    const f16* __restrict__ kt, const f16* __restrict__ vt, const f16* __restrict__ yq,
    f16* __restrict__ acc_ws, float* __restrict__ m_ws, float* __restrict__ l_ws)
{
    __shared__ f16 sKT[64 * 72];        // [key_local][c], row stride 144 B
    __shared__ f16 sVT[64 * 72];        // [channel][key_local]
    __shared__ f16 sPS[4 * 16 * 72];    // per-wave P [query_local][key_local]
    __shared__ float sAL[4 * 16];       // per-wave alpha[query]

    const int t = threadIdx.x;
    const int L = t & 63, w = t >> 6;
    const int g = L >> 4, c16 = L & 15;
    const int qb = blockIdx.x >> 3, sp = blockIdx.x & 7;
    const int n0 = qb * 64;
    const int mbase = sp * SPLEN;
    f16* psw = (f16*)sPS + w * 16 * 72;

    // Q fragments: Q[row][c] = yq_flat[row*64+c] (raw-reshape semantics)
    f16x8 qa[2];
    #pragma unroll
    for (int kc = 0; kc < 2; ++kc)
        qa[kc] = *(const f16x8*)(yq + (n0 + w * 16 + c16) * 64 + g * 8 + kc * 32);

    float mi = -1e30f;
    float li = 0.f;                     // PARTIAL row-sum (this lane's 16 key-columns)
    f32x4 acc[4];
    #pragma unroll
    for (int ct = 0; ct < 4; ++ct) acc[ct] = (f32x4){0.f, 0.f, 0.f, 0.f};

    for (int it = 0; it < ITERS; ++it) {
        const int m0 = mbase + it * 64;
        __syncthreads();
        #pragma unroll
        for (int rep = 0; rep < 2; ++rep) {
            int idx = t + rep * 256;
            int row = idx >> 3, ch = idx & 7;
            *(uint4*)&sKT[row * 72 + ch * 8] = *(const uint4*)&kt[(m0 + row) * 64 + ch * 8];
            *(uint4*)&sVT[row * 72 + ch * 8] = *(const uint4*)&vt[row * HW + m0 + ch * 8];
        }
        __syncthreads();

        // S^T = K Q^T : lane (g,c16) gets s[mt][j] = S[query w*16+c16][key m0+mt*16+4g+j]
        f32x4 s[4];
        #pragma unroll
        for (int mt = 0; mt < 4; ++mt) {
            f32x4 a0 = (f32x4){0.f, 0.f, 0.f, 0.f};
            #pragma unroll
            for (int kc = 0; kc < 2; ++kc) {
                f16x8 kb = *(const f16x8*)&sKT[(mt * 16 + c16) * 72 + g * 8 + kc * 32];
                a0 = __builtin_amdgcn_mfma_f32_16x16x32_f16(kb, qa[kc], a0, 0, 0, 0);
            }
            s[mt] = a0;
        }
        // threshold mask to ZERO
        #pragma unroll
        for (int mt = 0; mt < 4; ++mt)
            #pragma unroll
            for (int j = 0; j < 4; ++j)
                s[mt][j] = (fabsf(s[mt][j]) > 0.3f) ? s[mt][j] : 0.f;

        // local max (balanced tree) + 2 cross-lane reduces
        float x0 = fmaxf(fmaxf(s[0][0], s[0][1]), fmaxf(s[0][2], s[0][3]));
        float x1 = fmaxf(fmaxf(s[1][0], s[1][1]), fmaxf(s[1][2], s[1][3]));
        float x2 = fmaxf(fmaxf(s[2][0], s[2][1]), fmaxf(s[2][2], s[2][3]));
        float x3 = fmaxf(fmaxf(s[3][0], s[3][1]), fmaxf(s[3][2], s[3][3]));
        float mx = fmaxf(fmaxf(x0, x1), fmaxf(x2, x3));
        mx = fmaxf(mx, __shfl_xor(mx, 16, 64));
        mx = fmaxf(mx, __shfl_xor(mx, 32, 64));
        float mnew = fmaxf(mi, mx);
        float nL = mnew * LOG2E;
        float alpha = __builtin_amdgcn_exp2f(mi * LOG2E - nL);
        mi = mnew;

        // p = exp2(s*L2E - nL) via fma; local sum tree (no per-iter cross-lane)
        float p[16];
        #pragma unroll
        for (int mt = 0; mt < 4; ++mt)
            #pragma unroll
            for (int j = 0; j < 4; ++j)
                p[mt * 4 + j] = __builtin_amdgcn_exp2f(fmaf(s[mt][j], LOG2E, -nL));
        float q0 = (p[0] + p[1]) + (p[2] + p[3]);
        float q1 = (p[4] + p[5]) + (p[6] + p[7]);
        float q2 = (p[8] + p[9]) + (p[10] + p[11]);
        float q3 = (p[12] + p[13]) + (p[14] + p[15]);
        li = li * alpha + ((q0 + q1) + (q2 + q3));

        // write P: packed cvt + 4 aligned b64 stores
        #pragma unroll
        for (int mt = 0; mt < 4; ++mt) {
            unsigned u0 = __builtin_bit_cast(unsigned int,
                __builtin_amdgcn_cvt_pkrtz(p[mt * 4 + 0], p[mt * 4 + 1]));
            unsigned u1 = __builtin_bit_cast(unsigned int,
                __builtin_amdgcn_cvt_pkrtz(p[mt * 4 + 2], p[mt * 4 + 3]));
            uint2 uv; uv.x = u0; uv.y = u1;
            *(uint2*)&psw[c16 * 72 + mt * 16 + 4 * g] = uv;
        }

        // alpha distribution: 1 LDS write + 1 b128 broadcast read (same-wave RAW ordered)
        if (g == 0) sAL[w * 16 + c16] = alpha;
        f32x4 aj = *(const f32x4*)&sAL[w * 16 + 4 * g];   // alphas of queries 4g..4g+3
        #pragma unroll
        for (int ct = 0; ct < 4; ++ct)
            #pragma unroll
            for (int j = 0; j < 4; ++j) acc[ct][j] *= aj[j];

        // PV: A = P (A-layout from psw), B = V^T tile
        f16x8 pa[2];
        #pragma unroll
        for (int kc = 0; kc < 2; ++kc)
            pa[kc] = *(const f16x8*)&psw[c16 * 72 + g * 8 + kc * 32];
        #pragma unroll
        for (int ct = 0; ct < 4; ++ct)
            #pragma unroll
            for (int kc = 0; kc < 2; ++kc) {
                f16x8 vb = *(const f16x8*)&sVT[(ct * 16 + c16) * 72 + g * 8 + kc * 32];
                acc[ct] = __builtin_amdgcn_mfma_f32_16x16x32_f16(pa[kc], vb, acc[ct], 0, 0, 0);
            }
    }

    // finish partial row-sum (once, not per iter)
    float li_tot = li;
    li_tot += __shfl_xor(li_tot, 16, 64);
    li_tot += __shfl_xor(li_tot, 32, 64);

    // write partials (no divide; merge kernel combines splits)
    const int base = blockIdx.x;
    #pragma unroll
    for (int ct = 0; ct < 4; ++ct)
        #pragma unroll
        for (int j = 0; j < 4; ++j)
            acc_ws[base * 4096 + (w * 16 + 4 * g + j) * 64 + ct * 16 + c16] = (f16)acc[ct][j];
    if (g == 0) {
        m_ws[base * 64 + w * 16 + c16] = mi;    // unscaled units
        l_ws[base * 64 + w * 16 + c16] = li_tot;
    }
}

// ---------------- merge splits + residual + transpose; grid 576 (16-row sub-tiles)
__global__ __launch_bounds__(256) void merge_kernel(
    const f16* __restrict__ acc_ws, const float* __restrict__ m_ws, const float* __restrict__ l_ws,
    const float* __restrict__ x, float* __restrict__ out)
{
    __shared__ float wsh[SPLITS * 16];
    __shared__ float att[64 * 17];
    const int qb = blockIdx.x >> 2, sub = blockIdx.x & 3;
    const int r0 = sub * 16;
    const int t = threadIdx.x;
    if (t < 16) {
        int row = r0 + t;
        float ms = -1e30f;
        float mv[SPLITS];
        #pragma unroll
        for (int sp = 0; sp < SPLITS; ++sp) {
            mv[sp] = m_ws[(qb * SPLITS + sp) * 64 + row];
            ms = fmaxf(ms, mv[sp]);
        }
        float Lsum = 0.f, ev[SPLITS];
        #pragma unroll
        for (int sp = 0; sp < SPLITS; ++sp) {
            ev[sp] = __builtin_amdgcn_exp2f((mv[sp] - ms) * LOG2E);
            Lsum += l_ws[(qb * SPLITS + sp) * 64 + row] * ev[sp];
        }
        float inv = 1.f / Lsum;
        #pragma unroll
        for (int sp = 0; sp < SPLITS; ++sp)
            wsh[sp * 16 + t] = ev[sp] * inv;
    }
    __syncthreads();
    for (int i = t; i < 1024; i += 256) {
        int rr = i >> 6, c = i & 63;         // c fast -> coalesced acc_ws reads
        float v = 0.f;
        #pragma unroll
        for (int sp = 0; sp < SPLITS; ++sp)
            v += (float)acc_ws[(qb * SPLITS + sp) * 4096 + (r0 + rr) * 64 + c] * wsh[sp * 16 + rr];
        att[c * 17 + rr] = v;
    }
    __syncthreads();
    const int n0 = qb * 64 + r0;
    for (int i = t; i < 1024; i += 256) {
        int c = i >> 4, r = i & 15;
        int idx = c * HW + n0 + r;
        out[idx] = x[idx] + att[c * 17 + r];
    }
}

extern "C" void kernel_launch(void* const* d_in, const int* in_sizes, int n_in,
                              void* d_out, int out_size, void* d_ws, size_t ws_size,
                              hipStream_t stream)
{
    const float* x  = (const float*)d_in[0];
    const float* dW = (const float*)d_in[1];
    const float* db = (const float*)d_in[2];
    const float* cW = (const float*)d_in[3];
    const float* cb = (const float*)d_in[4];
    float* out = (float*)d_out;

    char* ws = (char*)d_ws;
    f16* kt     = (f16*)(ws);                        // 1,179,648 B
    f16* yq     = (f16*)(ws + 1179648);              // 1,179,648 B
    f16* vt     = (f16*)(ws + 2359296);              // 1,179,648 B
    f16* xpad   = (f16*)(ws + 3538944);              // 1,280,000 B
    f16* acc_ws = (f16*)(ws + 4818944);              // 9,437,184 B
    float* m_ws = (float*)(ws + 14256128);           //   294,912 B
    float* l_ws = (float*)(ws + 14551040);           //   294,912 B
                                                     // total 14,845,952 B

    prepad_kernel<<<dim3((CC * PW * PW + 255) / 256), dim3(256), 0, stream>>>(x, xpad);
    conv1x1_kernel<<<dim3(16 * 36), dim3(256), 0, stream>>>(x, cW, cb, vt);
    conv_dil_kernel<<<dim3(64 * 9), dim3(256), 0, stream>>>(xpad, dW, db, yq, kt);
    attn_kernel<<<dim3(144 * SPLITS), dim3(256), 0, stream>>>(kt, vt, yq, acc_ws, m_ws, l_ws);
    merge_kernel<<<dim3(576), dim3(256), 0, stream>>>(acc_ws, m_ws, l_ws, x, out);
}